// Round 1
// baseline (836.159 us; speedup 1.0000x reference)
//
#include <hip/hip_runtime.h>

// PixelShuffle depth-to-space, feature-major grouping.
// in : [B=8, X=256, Y=256, C=256] fp32
// out: [B=8, 512, 512, 64] fp32
// out[b, 2x+i, 2y+j, f] = in[b, x, y, f*4 + i*2 + j]
//
// One thread per (pixel, f-quad): 16 threads/pixel, each reads 64B contiguous
// (16 channels = 4 f-values x 4 (i,j) slots), register-transposes, and writes
// four float4s, one per (i,j). Both sides fully coalesced in 256B segments.

__global__ __launch_bounds__(256) void pixel_shuffle_kernel(
    const float4* __restrict__ in, float4* __restrict__ out) {
    const int tid = blockIdx.x * blockDim.x + threadIdx.x; // 0 .. 8*256*256*16-1
    const int t   = tid & 15;   // f-quad index (f = 4t .. 4t+3)
    const int pix = tid >> 4;   // b*65536 + x*256 + y
    const int y = pix & 255;
    const int x = (pix >> 8) & 255;
    const int b = pix >> 16;

    // Input float4 base: float index pix*256 + t*16 -> float4 index pix*64 + t*4
    const float4* src = in + pix * 64 + t * 4;
    float4 a0 = src[0];   // channels (4t+0)*4 + {0,1,2,3}  -> f=4t+0, ij=0..3
    float4 a1 = src[1];   // f=4t+1
    float4 a2 = src[2];   // f=4t+2
    float4 a3 = src[3];   // f=4t+3

    // Transpose: gather component ij across the 4 f-values.
    float4 o00 = make_float4(a0.x, a1.x, a2.x, a3.x); // (i,j)=(0,0)
    float4 o01 = make_float4(a0.y, a1.y, a2.y, a3.y); // (0,1)
    float4 o10 = make_float4(a0.z, a1.z, a2.z, a3.z); // (1,0)
    float4 o11 = make_float4(a0.w, a1.w, a2.w, a3.w); // (1,1)

    // Output float4 index: (b*2^24 + (2x+i)*2^15 + (2y+j)*2^6 + 4t) / 4
    //                    =  b*2^22 + (2x+i)*2^13 + (2y+j)*2^4 + t
    const int ob = (b << 22) + ((2 * x) << 13) + ((2 * y) << 4) + t;
    out[ob]                  = o00; // (0,0)
    out[ob + 16]             = o01; // (0,1): +2^4
    out[ob + (1 << 13)]      = o10; // (1,0)
    out[ob + (1 << 13) + 16] = o11; // (1,1)
}

extern "C" void kernel_launch(void* const* d_in, const int* in_sizes, int n_in,
                              void* d_out, int out_size, void* d_ws, size_t ws_size,
                              hipStream_t stream) {
    const float4* in  = (const float4*)d_in[0];
    float4*       out = (float4*)d_out;
    // total threads = B*X*Y*16 = 8*256*256*16 = 8,388,608
    const int n_threads = 8 * 256 * 256 * 16;
    const int block = 256;
    const int grid  = n_threads / block; // 32768
    pixel_shuffle_kernel<<<grid, block, 0, stream>>>(in, out);
}